// Round 1
// baseline (1307.302 us; speedup 1.0000x reference)
//
#include <hip/hip_runtime.h>
#include <math.h>

#define N_NODES 20000
#define N_EDGES 320000
#define F_IN    518
#define HIDDEN  256
#define DIM     128
#define NH      4

__device__ __forceinline__ float lrelu02(float x) { return x > 0.f ? x : 0.2f * x; }

// float atomic max via ordered-int encoding (valid for mixed signs)
__device__ __forceinline__ void atomicMaxF(float* addr, float v) {
    if (v >= 0.f) atomicMax((int*)addr, __float_as_int(v));
    else          atomicMin((unsigned int*)addr, __float_as_uint(v));
}

// ---------------- GEMM: C[M,N] = act(A[M,K] @ B[K,N] + bias) ----------------
__global__ __launch_bounds__(256) void gemm_bias_act(
    const float* __restrict__ A, const float* __restrict__ B,
    const float* __restrict__ bias, float* __restrict__ C,
    int M, int N, int K, int act)
{
    __shared__ float As[16][68];   // [k][row], +4 pad keeps 16B alignment, breaks conflicts
    __shared__ float Bs[16][64];   // [k][col]
    const int tid = threadIdx.x;
    const int tx = tid & 15, ty = tid >> 4;
    const int row0 = blockIdx.y * 64, col0 = blockIdx.x * 64;

    float acc[4][4] = {{0.f,0.f,0.f,0.f},{0.f,0.f,0.f,0.f},{0.f,0.f,0.f,0.f},{0.f,0.f,0.f,0.f}};

    for (int kt = 0; kt < K; kt += 16) {
        #pragma unroll
        for (int i = tid; i < 64 * 16; i += 256) {
            int r = i >> 4, k = i & 15;
            int gr = row0 + r, gk = kt + k;
            As[k][r] = (gr < M && gk < K) ? A[(size_t)gr * K + gk] : 0.f;
        }
        #pragma unroll
        for (int i = tid; i < 16 * 64; i += 256) {
            int k = i >> 6, c = i & 63;
            int gk = kt + k;
            Bs[k][c] = (gk < K) ? B[(size_t)gk * N + col0 + c] : 0.f;
        }
        __syncthreads();
        #pragma unroll
        for (int k = 0; k < 16; ++k) {
            float a0 = As[k][ty*4+0], a1 = As[k][ty*4+1], a2 = As[k][ty*4+2], a3 = As[k][ty*4+3];
            float b0 = Bs[k][tx*4+0], b1 = Bs[k][tx*4+1], b2 = Bs[k][tx*4+2], b3 = Bs[k][tx*4+3];
            acc[0][0] += a0*b0; acc[0][1] += a0*b1; acc[0][2] += a0*b2; acc[0][3] += a0*b3;
            acc[1][0] += a1*b0; acc[1][1] += a1*b1; acc[1][2] += a1*b2; acc[1][3] += a1*b3;
            acc[2][0] += a2*b0; acc[2][1] += a2*b1; acc[2][2] += a2*b2; acc[2][3] += a2*b3;
            acc[3][0] += a3*b0; acc[3][1] += a3*b1; acc[3][2] += a3*b2; acc[3][3] += a3*b3;
        }
        __syncthreads();
    }

    const int gc = col0 + tx * 4;
    float bb0 = bias ? bias[gc+0] : 0.f;
    float bb1 = bias ? bias[gc+1] : 0.f;
    float bb2 = bias ? bias[gc+2] : 0.f;
    float bb3 = bias ? bias[gc+3] : 0.f;
    #pragma unroll
    for (int i = 0; i < 4; ++i) {
        int gr = row0 + ty * 4 + i;
        if (gr < M) {
            float4 v;
            v.x = acc[i][0] + bb0; v.y = acc[i][1] + bb1;
            v.z = acc[i][2] + bb2; v.w = acc[i][3] + bb3;
            if (act) { v.x = fmaxf(v.x, 0.f); v.y = fmaxf(v.y, 0.f);
                       v.z = fmaxf(v.z, 0.f); v.w = fmaxf(v.w, 0.f); }
            *(float4*)(C + (size_t)gr * N + gc) = v;
        }
    }
}

// ------------- a_s[n,h], a_d[n,h]: one wave per (n,h) pair -------------
__global__ __launch_bounds__(256) void as_ad_kernel(
    const float* __restrict__ hfeat, const float* __restrict__ atts,
    const float* __restrict__ attd, float* __restrict__ a_s, float* __restrict__ a_d)
{
    const int gw = blockIdx.x * 4 + (threadIdx.x >> 6);  // global wave = (n,h) pair
    const int lane = threadIdx.x & 63;
    if (gw >= N_NODES * NH) return;
    const int n = gw >> 2, h = gw & 3;
    const float* hp = hfeat + (size_t)n * (NH * DIM) + h * DIM;
    float2 hv = *(const float2*)(hp + lane * 2);
    float2 sv = *(const float2*)(atts + h * DIM + lane * 2);
    float2 dv = *(const float2*)(attd + h * DIM + lane * 2);
    float s = hv.x * sv.x + hv.y * sv.y;
    float d = hv.x * dv.x + hv.y * dv.y;
    #pragma unroll
    for (int off = 32; off > 0; off >>= 1) {
        s += __shfl_down(s, off);
        d += __shfl_down(d, off);
    }
    if (lane == 0) { a_s[n * 4 + h] = s; a_d[n * 4 + h] = d; }
}

// ------------- rel attention table[r,h] = rel_emb[r] @ (lin_e[:,h,:] @ att_e[h]) -------------
__global__ __launch_bounds__(128) void rel_table_kernel(
    const float* __restrict__ rel_emb, const float* __restrict__ line,
    const float* __restrict__ atte, float* __restrict__ table)
{
    __shared__ float we[32][NH];
    const int tid = threadIdx.x;         // 128 threads
    const int k = tid >> 2, h = tid & 3; // k<32, h<4
    float acc = 0.f;
    for (int d = 0; d < DIM; ++d)
        acc += line[(size_t)k * (NH * DIM) + h * DIM + d] * atte[h * DIM + d];
    we[k][h] = acc;
    __syncthreads();
    if (tid < 26 * NH) {
        int r = tid >> 2, hh = tid & 3;
        float t = 0.f;
        for (int kk = 0; kk < 32; ++kk) t += rel_emb[r * 32 + kk] * we[kk][hh];
        table[r * 4 + hh] = t;
    }
}

// ------------- per-edge: degree count + sum of table rows per dst -------------
__global__ __launch_bounds__(256) void edge_stats_kernel(
    const int* __restrict__ dst, const int* __restrict__ etype,
    const float* __restrict__ table, float* __restrict__ cnt, float* __restrict__ aesum)
{
    const int e = blockIdx.x * blockDim.x + threadIdx.x;
    if (e >= N_EDGES) return;
    const int d = dst[e], t = etype[e];
    float4 tv = *(const float4*)(table + t * 4);
    atomicAdd(&cnt[d], 1.0f);
    atomicAdd(&aesum[d * 4 + 0], tv.x);
    atomicAdd(&aesum[d * 4 + 1], tv.y);
    atomicAdd(&aesum[d * 4 + 2], tv.z);
    atomicAdd(&aesum[d * 4 + 3], tv.w);
}

// ------------- self-loop logits; init running max -------------
__global__ __launch_bounds__(256) void node_self_kernel(
    const float* __restrict__ a_s, const float* __restrict__ a_d,
    const float* __restrict__ cnt, const float* __restrict__ aesum,
    float* __restrict__ slog, float* __restrict__ mbuf)
{
    const int n = blockIdx.x * blockDim.x + threadIdx.x;
    if (n >= N_NODES) return;
    const float inv = 1.0f / fmaxf(cnt[n], 1.0f);
    float4 as4 = *(const float4*)(a_s + n * 4);
    float4 ad4 = *(const float4*)(a_d + n * 4);
    float4 ae4 = *(const float4*)(aesum + n * 4);
    float4 l;
    l.x = lrelu02(as4.x + ad4.x + ae4.x * inv);
    l.y = lrelu02(as4.y + ad4.y + ae4.y * inv);
    l.z = lrelu02(as4.z + ad4.z + ae4.z * inv);
    l.w = lrelu02(as4.w + ad4.w + ae4.w * inv);
    *(float4*)(slog + n * 4) = l;
    *(float4*)(mbuf + n * 4) = l;
}

// ------------- edge logits + segment max -------------
__global__ __launch_bounds__(256) void edge_logit_kernel(
    const int* __restrict__ src, const int* __restrict__ dst, const int* __restrict__ etype,
    const float* __restrict__ a_s, const float* __restrict__ a_d,
    const float* __restrict__ table, float* __restrict__ logit, float* __restrict__ mbuf)
{
    const int e = blockIdx.x * blockDim.x + threadIdx.x;
    if (e >= N_EDGES) return;
    const int s = src[e], d = dst[e], t = etype[e];
    float4 as4 = *(const float4*)(a_s + s * 4);
    float4 ad4 = *(const float4*)(a_d + d * 4);
    float4 tv  = *(const float4*)(table + t * 4);
    float4 l;
    l.x = lrelu02(as4.x + ad4.x + tv.x);
    l.y = lrelu02(as4.y + ad4.y + tv.y);
    l.z = lrelu02(as4.z + ad4.z + tv.z);
    l.w = lrelu02(as4.w + ad4.w + tv.w);
    *(float4*)(logit + (size_t)e * 4) = l;
    atomicMaxF(&mbuf[d * 4 + 0], l.x);
    atomicMaxF(&mbuf[d * 4 + 1], l.y);
    atomicMaxF(&mbuf[d * 4 + 2], l.z);
    atomicMaxF(&mbuf[d * 4 + 3], l.w);
}

// ------------- exp(logit - max), accumulate denom (p stored in-place) -------------
__global__ __launch_bounds__(256) void edge_exp_kernel(
    const int* __restrict__ dst, float* __restrict__ p,
    const float* __restrict__ mbuf, float* __restrict__ denom)
{
    const int e = blockIdx.x * blockDim.x + threadIdx.x;
    if (e >= N_EDGES) return;
    const int d = dst[e];
    float4 l = *(const float4*)(p + (size_t)e * 4);
    float4 m = *(const float4*)(mbuf + d * 4);
    float4 pe;
    pe.x = __expf(l.x - m.x); pe.y = __expf(l.y - m.y);
    pe.z = __expf(l.z - m.z); pe.w = __expf(l.w - m.w);
    *(float4*)(p + (size_t)e * 4) = pe;
    atomicAdd(&denom[d * 4 + 0], pe.x);
    atomicAdd(&denom[d * 4 + 1], pe.y);
    atomicAdd(&denom[d * 4 + 2], pe.z);
    atomicAdd(&denom[d * 4 + 3], pe.w);
}

// ------------- finalize denom w/ self term; init out with self-loop message -------------
__global__ __launch_bounds__(128) void node_out_kernel(
    const float* __restrict__ hfeat, const float* __restrict__ slog,
    const float* __restrict__ mbuf, const float* __restrict__ denom,
    float* __restrict__ invd, float* __restrict__ out)
{
    const int n = blockIdx.x;
    const int d = threadIdx.x;
    float4 sl = *(const float4*)(slog + n * 4);
    float4 mx = *(const float4*)(mbuf + n * 4);
    float4 dn = *(const float4*)(denom + n * 4);
    float p0 = __expf(sl.x - mx.x), p1 = __expf(sl.y - mx.y);
    float p2 = __expf(sl.z - mx.z), p3 = __expf(sl.w - mx.w);
    float i0 = 0.25f / (dn.x + p0 + 1e-16f);   // 0.25 = head-mean folded in
    float i1 = 0.25f / (dn.y + p1 + 1e-16f);
    float i2 = 0.25f / (dn.z + p2 + 1e-16f);
    float i3 = 0.25f / (dn.w + p3 + 1e-16f);
    const float* hp = hfeat + (size_t)n * (NH * DIM);
    float o = p0*i0*hp[d] + p1*i1*hp[DIM + d] + p2*i2*hp[2*DIM + d] + p3*i3*hp[3*DIM + d];
    out[(size_t)n * DIM + d] = o;
    if (d == 0) {
        float4 v; v.x = i0; v.y = i1; v.z = i2; v.w = i3;
        *(float4*)(invd + n * 4) = v;
    }
}

// ------------- heavy pass: one wave per edge, head-collapsed scatter-add -------------
__global__ __launch_bounds__(256) void edge_agg_kernel(
    const int* __restrict__ src, const int* __restrict__ dst,
    const float* __restrict__ p, const float* __restrict__ invd,
    const float* __restrict__ hfeat, float* __restrict__ out)
{
    const int gw = blockIdx.x * 4 + (threadIdx.x >> 6);   // global wave = edge
    const int lane = threadIdx.x & 63;
    if (gw >= N_EDGES) return;
    const int s = src[gw], d = dst[gw];
    float4 pv = *(const float4*)(p + (size_t)gw * 4);
    float4 iv = *(const float4*)(invd + d * 4);
    const float w0 = pv.x * iv.x, w1 = pv.y * iv.y, w2 = pv.z * iv.z, w3 = pv.w * iv.w;
    const float* hp = hfeat + (size_t)s * (NH * DIM);
    float m0 = w0*hp[lane]      + w1*hp[DIM + lane]     + w2*hp[2*DIM + lane]     + w3*hp[3*DIM + lane];
    float m1 = w0*hp[64 + lane] + w1*hp[DIM + 64 + lane]+ w2*hp[2*DIM + 64 + lane]+ w3*hp[3*DIM + 64 + lane];
    atomicAdd(&out[(size_t)d * DIM + lane], m0);
    atomicAdd(&out[(size_t)d * DIM + 64 + lane], m1);
}

// ------------- out = relu(out + bias), in place -------------
__global__ __launch_bounds__(256) void relu_bias_kernel(
    float* __restrict__ x, const float* __restrict__ bias, int total)
{
    const int i = blockIdx.x * blockDim.x + threadIdx.x;
    if (i >= total) return;
    x[i] = fmaxf(x[i] + bias[i & (DIM - 1)], 0.f);
}

extern "C" void kernel_launch(void* const* d_in, const int* in_sizes, int n_in,
                              void* d_out, int out_size, void* d_ws, size_t ws_size,
                              hipStream_t stream)
{
    const float* x       = (const float*)d_in[0];
    const int*   eidx    = (const int*)d_in[1];
    const int*   etype   = (const int*)d_in[2];
    const float* w1      = (const float*)d_in[3];
    const float* b1      = (const float*)d_in[4];
    const float* w2      = (const float*)d_in[5];
    const float* b2      = (const float*)d_in[6];
    const float* rel_emb = (const float*)d_in[7];
    const float* lin[2]  = {(const float*)d_in[8],  (const float*)d_in[14]};
    const float* line[2] = {(const float*)d_in[9],  (const float*)d_in[15]};
    const float* atts[2] = {(const float*)d_in[10], (const float*)d_in[16]};
    const float* attd[2] = {(const float*)d_in[11], (const float*)d_in[17]};
    const float* atte[2] = {(const float*)d_in[12], (const float*)d_in[18]};
    const float* bias[2] = {(const float*)d_in[13], (const float*)d_in[19]};
    const int* src = eidx;              // edge_index row 0
    const int* dst = eidx + N_EDGES;    // edge_index row 1

    float* wsf   = (float*)d_ws;
    float* hfeat = wsf;                                   // N*512 (encoder hidden N*256 aliases here)
    float* xbuf  = hfeat + (size_t)N_NODES * (NH * DIM);  // N*128
    float* edgep = xbuf + (size_t)N_NODES * DIM;          // E*4
    float* a_s   = edgep + (size_t)N_EDGES * 4;           // N*4
    float* a_d   = a_s + N_NODES * 4;
    float* cnt   = a_d + N_NODES * 4;                     // N
    float* aesum = cnt + N_NODES;                         // N*4
    float* slog  = aesum + N_NODES * 4;                   // N*4
    float* mbuf  = slog + N_NODES * 4;                    // N*4
    float* denom = mbuf + N_NODES * 4;                    // N*4
    float* invd  = denom + N_NODES * 4;                   // N*4
    float* table = invd + N_NODES * 4;                    // 128

    const int mtiles = (N_NODES + 63) / 64;

    // node encoder: hh = relu(x@w1+b1) ; xbuf = hh@w2+b2   (hh aliases hfeat region)
    gemm_bias_act<<<dim3(HIDDEN / 64, mtiles), 256, 0, stream>>>(x, w1, b1, hfeat, N_NODES, HIDDEN, F_IN, 1);
    gemm_bias_act<<<dim3(DIM / 64, mtiles), 256, 0, stream>>>(hfeat, w2, b2, xbuf, N_NODES, DIM, HIDDEN, 0);

    for (int L = 0; L < 2; ++L) {
        float* outp = (L == 0) ? xbuf : (float*)d_out;  // L0 out aliases xbuf (free after GEMM)

        gemm_bias_act<<<dim3((NH * DIM) / 64, mtiles), 256, 0, stream>>>(
            xbuf, lin[L], nullptr, hfeat, N_NODES, NH * DIM, DIM, 0);
        as_ad_kernel<<<N_NODES, 256, 0, stream>>>(hfeat, atts[L], attd[L], a_s, a_d);
        rel_table_kernel<<<1, 128, 0, stream>>>(rel_emb, line[L], atte[L], table);
        hipMemsetAsync(cnt, 0, N_NODES * sizeof(float), stream);
        hipMemsetAsync(aesum, 0, N_NODES * 4 * sizeof(float), stream);
        hipMemsetAsync(denom, 0, N_NODES * 4 * sizeof(float), stream);
        edge_stats_kernel<<<(N_EDGES + 255) / 256, 256, 0, stream>>>(dst, etype, table, cnt, aesum);
        node_self_kernel<<<(N_NODES + 255) / 256, 256, 0, stream>>>(a_s, a_d, cnt, aesum, slog, mbuf);
        edge_logit_kernel<<<(N_EDGES + 255) / 256, 256, 0, stream>>>(src, dst, etype, a_s, a_d, table, edgep, mbuf);
        edge_exp_kernel<<<(N_EDGES + 255) / 256, 256, 0, stream>>>(dst, edgep, mbuf, denom);
        node_out_kernel<<<N_NODES, 128, 0, stream>>>(hfeat, slog, mbuf, denom, invd, outp);
        edge_agg_kernel<<<N_EDGES / 4, 256, 0, stream>>>(src, dst, edgep, invd, hfeat, outp);
        relu_bias_kernel<<<(N_NODES * DIM + 255) / 256, 256, 0, stream>>>(outp, bias[L], N_NODES * DIM);
    }
}

// Round 2
// 1036.012 us; speedup vs baseline: 1.2619x; 1.2619x over previous
//
#include <hip/hip_runtime.h>
#include <math.h>

#define N_NODES 20000
#define N_EDGES 320000
#define F_IN    518
#define HIDDEN  256
#define DIM     128
#define NH      4

#define BM 128
#define BN 64
#define BK 16

__device__ __forceinline__ float lrelu02(float x) { return x > 0.f ? x : 0.2f * x; }

// ---------------- GEMM: C[M,N] = act(A[M,K] @ B[K,N] + bias) ----------------
// 128x64 block tile, 8x4 per-thread microtile, k-major LDS, float4 frag reads.
__global__ __launch_bounds__(256) void gemm_bias_act(
    const float* __restrict__ A, const float* __restrict__ B,
    const float* __restrict__ bias, float* __restrict__ C,
    int M, int N, int K, int act)
{
    __shared__ float As[BK][BM + 4];   // k-major; +4 keeps 16B align, breaks stride conflicts
    __shared__ float Bs[BK][BN + 4];
    const int tid = threadIdx.x;
    const int tx = tid & 15;           // n quad  -> col = tx*4
    const int ty = tid >> 4;           // m oct   -> row = ty*8
    const int row0 = blockIdx.y * BM, col0 = blockIdx.x * BN;

    // A staging: thread loads 8 consecutive k of one row (as 4x float2, 8B-aligned since K even)
    const int arow = tid >> 1;         // 0..127
    const int ak0  = (tid & 1) * 8;    // 0 or 8
    const int gr_a = row0 + arow;

    // B staging: thread loads one float4 (16B aligned: N % 4 == 0, bn % 4 == 0)
    const int bk = tid >> 4;           // 0..15
    const int bn = (tid & 15) * 4;

    float acc[8][4] = {};

    for (int kt = 0; kt < K; kt += BK) {
        float2 av[4];
        #pragma unroll
        for (int j = 0; j < 4; ++j) {
            int gk = kt + ak0 + 2 * j;
            float2 v = {0.f, 0.f};
            if (gr_a < M && gk < K) {
                const float* p = A + (size_t)gr_a * K + gk;
                if (gk + 1 < K) v = *(const float2*)p;
                else            v.x = *p;
            }
            av[j] = v;
        }
        float4 bv = {0.f, 0.f, 0.f, 0.f};
        {
            int gk = kt + bk;
            if (gk < K) bv = *(const float4*)(B + (size_t)gk * N + col0 + bn);
        }

        __syncthreads();   // previous iter's frag reads done before overwrite
        #pragma unroll
        for (int j = 0; j < 4; ++j) {
            As[ak0 + 2*j    ][arow] = av[j].x;
            As[ak0 + 2*j + 1][arow] = av[j].y;
        }
        *(float4*)&Bs[bk][bn] = bv;
        __syncthreads();

        #pragma unroll
        for (int k = 0; k < BK; ++k) {
            float4 a0 = *(const float4*)&As[k][ty * 8];
            float4 a1 = *(const float4*)&As[k][ty * 8 + 4];
            float4 b  = *(const float4*)&Bs[k][tx * 4];
            float am[8] = {a0.x, a0.y, a0.z, a0.w, a1.x, a1.y, a1.z, a1.w};
            #pragma unroll
            for (int i = 0; i < 8; ++i) {
                acc[i][0] += am[i] * b.x;
                acc[i][1] += am[i] * b.y;
                acc[i][2] += am[i] * b.z;
                acc[i][3] += am[i] * b.w;
            }
        }
    }

    const int gc = col0 + tx * 4;
    float bb0 = bias ? bias[gc + 0] : 0.f;
    float bb1 = bias ? bias[gc + 1] : 0.f;
    float bb2 = bias ? bias[gc + 2] : 0.f;
    float bb3 = bias ? bias[gc + 3] : 0.f;
    #pragma unroll
    for (int i = 0; i < 8; ++i) {
        int gr = row0 + ty * 8 + i;
        if (gr < M) {
            float4 v;
            v.x = acc[i][0] + bb0; v.y = acc[i][1] + bb1;
            v.z = acc[i][2] + bb2; v.w = acc[i][3] + bb3;
            if (act) { v.x = fmaxf(v.x, 0.f); v.y = fmaxf(v.y, 0.f);
                       v.z = fmaxf(v.z, 0.f); v.w = fmaxf(v.w, 0.f); }
            *(float4*)(C + (size_t)gr * N + gc) = v;
        }
    }
}

// ------------- a_s[n,h], a_d[n,h]: one wave per (n,h) pair -------------
__global__ __launch_bounds__(256) void as_ad_kernel(
    const float* __restrict__ hfeat, const float* __restrict__ atts,
    const float* __restrict__ attd, float* __restrict__ a_s, float* __restrict__ a_d)
{
    const int gw = blockIdx.x * 4 + (threadIdx.x >> 6);
    const int lane = threadIdx.x & 63;
    if (gw >= N_NODES * NH) return;
    const int n = gw >> 2, h = gw & 3;
    const float* hp = hfeat + (size_t)n * (NH * DIM) + h * DIM;
    float2 hv = *(const float2*)(hp + lane * 2);
    float2 sv = *(const float2*)(atts + h * DIM + lane * 2);
    float2 dv = *(const float2*)(attd + h * DIM + lane * 2);
    float s = hv.x * sv.x + hv.y * sv.y;
    float d = hv.x * dv.x + hv.y * dv.y;
    #pragma unroll
    for (int off = 32; off > 0; off >>= 1) {
        s += __shfl_down(s, off);
        d += __shfl_down(d, off);
    }
    if (lane == 0) { a_s[n * 4 + h] = s; a_d[n * 4 + h] = d; }
}

// ------------- rel attention table[r,h] = rel_emb[r] @ (lin_e[:,h,:] @ att_e[h]) -------------
__global__ __launch_bounds__(128) void rel_table_kernel(
    const float* __restrict__ rel_emb, const float* __restrict__ line,
    const float* __restrict__ atte, float* __restrict__ table)
{
    __shared__ float we[32][NH];
    const int tid = threadIdx.x;
    const int k = tid >> 2, h = tid & 3;
    float acc = 0.f;
    for (int d = 0; d < DIM; ++d)
        acc += line[(size_t)k * (NH * DIM) + h * DIM + d] * atte[h * DIM + d];
    we[k][h] = acc;
    __syncthreads();
    if (tid < 26 * NH) {
        int r = tid >> 2, hh = tid & 3;
        float t = 0.f;
        for (int kk = 0; kk < 32; ++kk) t += rel_emb[r * 32 + kk] * we[kk][hh];
        table[r * 4 + hh] = t;
    }
}

// ------------- per-edge: degree count + sum of table rows per dst -------------
__global__ __launch_bounds__(256) void edge_stats_kernel(
    const int* __restrict__ dst, const int* __restrict__ etype,
    const float* __restrict__ table, float* __restrict__ cnt, float* __restrict__ aesum)
{
    const int e = blockIdx.x * blockDim.x + threadIdx.x;
    if (e >= N_EDGES) return;
    const int d = dst[e], t = etype[e];
    float4 tv = *(const float4*)(table + t * 4);
    atomicAdd(&cnt[d], 1.0f);
    atomicAdd(&aesum[d * 4 + 0], tv.x);
    atomicAdd(&aesum[d * 4 + 1], tv.y);
    atomicAdd(&aesum[d * 4 + 2], tv.z);
    atomicAdd(&aesum[d * 4 + 3], tv.w);
}

// ------------- self-loop: p_self = exp(logit); denom initialized with it -------------
// (segment-max dropped: softmax is shift-invariant; logits are O(1) here, exp is fp32-safe)
__global__ __launch_bounds__(256) void node_self_exp_kernel(
    const float* __restrict__ a_s, const float* __restrict__ a_d,
    const float* __restrict__ cnt, const float* __restrict__ aesum,
    float* __restrict__ pself, float* __restrict__ denom)
{
    const int n = blockIdx.x * blockDim.x + threadIdx.x;
    if (n >= N_NODES) return;
    const float inv = 1.0f / fmaxf(cnt[n], 1.0f);
    float4 as4 = *(const float4*)(a_s + n * 4);
    float4 ad4 = *(const float4*)(a_d + n * 4);
    float4 ae4 = *(const float4*)(aesum + n * 4);
    float4 p;
    p.x = __expf(lrelu02(as4.x + ad4.x + ae4.x * inv));
    p.y = __expf(lrelu02(as4.y + ad4.y + ae4.y * inv));
    p.z = __expf(lrelu02(as4.z + ad4.z + ae4.z * inv));
    p.w = __expf(lrelu02(as4.w + ad4.w + ae4.w * inv));
    *(float4*)(pself + n * 4) = p;
    *(float4*)(denom + n * 4) = p;   // plain store; edge atomics come in a later kernel
}

// ------------- edge p = exp(logit); accumulate denom -------------
__global__ __launch_bounds__(256) void edge_logit_exp_kernel(
    const int* __restrict__ src, const int* __restrict__ dst, const int* __restrict__ etype,
    const float* __restrict__ a_s, const float* __restrict__ a_d,
    const float* __restrict__ table, float* __restrict__ p, float* __restrict__ denom)
{
    const int e = blockIdx.x * blockDim.x + threadIdx.x;
    if (e >= N_EDGES) return;
    const int s = src[e], d = dst[e], t = etype[e];
    float4 as4 = *(const float4*)(a_s + s * 4);
    float4 ad4 = *(const float4*)(a_d + d * 4);
    float4 tv  = *(const float4*)(table + t * 4);
    float4 pe;
    pe.x = __expf(lrelu02(as4.x + ad4.x + tv.x));
    pe.y = __expf(lrelu02(as4.y + ad4.y + tv.y));
    pe.z = __expf(lrelu02(as4.z + ad4.z + tv.z));
    pe.w = __expf(lrelu02(as4.w + ad4.w + tv.w));
    *(float4*)(p + (size_t)e * 4) = pe;
    atomicAdd(&denom[d * 4 + 0], pe.x);
    atomicAdd(&denom[d * 4 + 1], pe.y);
    atomicAdd(&denom[d * 4 + 2], pe.z);
    atomicAdd(&denom[d * 4 + 3], pe.w);
}

// ------------- invd = 0.25/(denom+eps); out initialized with self-loop message -------------
__global__ __launch_bounds__(128) void node_out_kernel(
    const float* __restrict__ hfeat, const float* __restrict__ pself,
    const float* __restrict__ denom, float* __restrict__ invd, float* __restrict__ out)
{
    const int n = blockIdx.x;
    const int d = threadIdx.x;
    float4 ps = *(const float4*)(pself + n * 4);
    float4 dn = *(const float4*)(denom + n * 4);
    float i0 = 0.25f / (dn.x + 1e-16f);   // 0.25 = head-mean folded in
    float i1 = 0.25f / (dn.y + 1e-16f);
    float i2 = 0.25f / (dn.z + 1e-16f);
    float i3 = 0.25f / (dn.w + 1e-16f);
    const float* hp = hfeat + (size_t)n * (NH * DIM);
    float o = ps.x*i0*hp[d] + ps.y*i1*hp[DIM + d] + ps.z*i2*hp[2*DIM + d] + ps.w*i3*hp[3*DIM + d];
    out[(size_t)n * DIM + d] = o;
    if (d == 0) {
        float4 v; v.x = i0; v.y = i1; v.z = i2; v.w = i3;
        *(float4*)(invd + n * 4) = v;
    }
}

// ------------- heavy pass: one wave per edge, head-collapsed scatter-add -------------
__global__ __launch_bounds__(256) void edge_agg_kernel(
    const int* __restrict__ src, const int* __restrict__ dst,
    const float* __restrict__ p, const float* __restrict__ invd,
    const float* __restrict__ hfeat, float* __restrict__ out)
{
    const int gw = blockIdx.x * 4 + (threadIdx.x >> 6);
    const int lane = threadIdx.x & 63;
    if (gw >= N_EDGES) return;
    const int s = src[gw], d = dst[gw];
    float4 pv = *(const float4*)(p + (size_t)gw * 4);
    float4 iv = *(const float4*)(invd + d * 4);
    const float w0 = pv.x * iv.x, w1 = pv.y * iv.y, w2 = pv.z * iv.z, w3 = pv.w * iv.w;
    const float* hp = hfeat + (size_t)s * (NH * DIM);
    float m0 = w0*hp[lane]      + w1*hp[DIM + lane]      + w2*hp[2*DIM + lane]      + w3*hp[3*DIM + lane];
    float m1 = w0*hp[64 + lane] + w1*hp[DIM + 64 + lane] + w2*hp[2*DIM + 64 + lane] + w3*hp[3*DIM + 64 + lane];
    atomicAdd(&out[(size_t)d * DIM + lane], m0);
    atomicAdd(&out[(size_t)d * DIM + 64 + lane], m1);
}

// ------------- out = relu(out + bias), in place -------------
__global__ __launch_bounds__(256) void relu_bias_kernel(
    float* __restrict__ x, const float* __restrict__ bias, int total)
{
    const int i = blockIdx.x * blockDim.x + threadIdx.x;
    if (i >= total) return;
    x[i] = fmaxf(x[i] + bias[i & (DIM - 1)], 0.f);
}

extern "C" void kernel_launch(void* const* d_in, const int* in_sizes, int n_in,
                              void* d_out, int out_size, void* d_ws, size_t ws_size,
                              hipStream_t stream)
{
    const float* x       = (const float*)d_in[0];
    const int*   eidx    = (const int*)d_in[1];
    const int*   etype   = (const int*)d_in[2];
    const float* w1      = (const float*)d_in[3];
    const float* b1      = (const float*)d_in[4];
    const float* w2      = (const float*)d_in[5];
    const float* b2      = (const float*)d_in[6];
    const float* rel_emb = (const float*)d_in[7];
    const float* lin[2]  = {(const float*)d_in[8],  (const float*)d_in[14]};
    const float* line[2] = {(const float*)d_in[9],  (const float*)d_in[15]};
    const float* atts[2] = {(const float*)d_in[10], (const float*)d_in[16]};
    const float* attd[2] = {(const float*)d_in[11], (const float*)d_in[17]};
    const float* atte[2] = {(const float*)d_in[12], (const float*)d_in[18]};
    const float* bias[2] = {(const float*)d_in[13], (const float*)d_in[19]};
    const int* src = eidx;
    const int* dst = eidx + N_EDGES;

    float* wsf   = (float*)d_ws;
    float* hfeat = wsf;                                   // N*512 (encoder hidden aliases here)
    float* xbuf  = hfeat + (size_t)N_NODES * (NH * DIM);  // N*128
    float* edgep = xbuf + (size_t)N_NODES * DIM;          // E*4
    float* a_s   = edgep + (size_t)N_EDGES * 4;           // N*4
    float* a_d   = a_s + N_NODES * 4;                     // N*4
    float* cnt   = a_d + N_NODES * 4;                     // N      } contiguous for
    float* aesum = cnt + N_NODES;                         // N*4    } single memset
    float* pself = aesum + N_NODES * 4;                   // N*4
    float* denom = pself + N_NODES * 4;                   // N*4
    float* invd  = denom + N_NODES * 4;                   // N*4
    float* table = invd + N_NODES * 4;                    // 128

    const int mtiles = (N_NODES + BM - 1) / BM;

    // node encoder: hh = relu(x@w1+b1); xbuf = hh@w2+b2  (hh aliases hfeat region)
    gemm_bias_act<<<dim3(HIDDEN / BN, mtiles), 256, 0, stream>>>(x, w1, b1, hfeat, N_NODES, HIDDEN, F_IN, 1);
    gemm_bias_act<<<dim3(DIM / BN, mtiles), 256, 0, stream>>>(hfeat, w2, b2, xbuf, N_NODES, DIM, HIDDEN, 0);

    for (int L = 0; L < 2; ++L) {
        float* outp = (L == 0) ? xbuf : (float*)d_out;   // L0 out aliases xbuf (dead after gemm)

        gemm_bias_act<<<dim3((NH * DIM) / BN, mtiles), 256, 0, stream>>>(
            xbuf, lin[L], nullptr, hfeat, N_NODES, NH * DIM, DIM, 0);
        as_ad_kernel<<<N_NODES, 256, 0, stream>>>(hfeat, atts[L], attd[L], a_s, a_d);
        rel_table_kernel<<<1, 128, 0, stream>>>(rel_emb, line[L], atte[L], table);
        hipMemsetAsync(cnt, 0, N_NODES * 5 * sizeof(float), stream);   // cnt + aesum contiguous
        edge_stats_kernel<<<(N_EDGES + 255) / 256, 256, 0, stream>>>(dst, etype, table, cnt, aesum);
        node_self_exp_kernel<<<(N_NODES + 255) / 256, 256, 0, stream>>>(a_s, a_d, cnt, aesum, pself, denom);
        edge_logit_exp_kernel<<<(N_EDGES + 255) / 256, 256, 0, stream>>>(src, dst, etype, a_s, a_d, table, edgep, denom);
        node_out_kernel<<<N_NODES, 128, 0, stream>>>(hfeat, pself, denom, invd, outp);
        edge_agg_kernel<<<N_EDGES / 4, 256, 0, stream>>>(src, dst, edgep, invd, hfeat, outp);
        relu_bias_kernel<<<(N_NODES * DIM + 255) / 256, 256, 0, stream>>>(outp, bias[L], N_NODES * DIM);
    }
}

// Round 3
// 666.833 us; speedup vs baseline: 1.9605x; 1.5536x over previous
//
#include <hip/hip_runtime.h>
#include <math.h>

#define N_NODES 20000
#define N_EDGES 320000
#define F_IN    518
#define HIDDEN  256
#define DIM     128
#define NH      4

#define BM 128
#define BN 64
#define BK 16

__device__ __forceinline__ float lrelu02(float x) { return x > 0.f ? x : 0.2f * x; }

// ---------------- GEMM: C[M,N] = act(A[M,K] @ B[K,N] + bias) ----------------
__global__ __launch_bounds__(256) void gemm_bias_act(
    const float* __restrict__ A, const float* __restrict__ B,
    const float* __restrict__ bias, float* __restrict__ C,
    int M, int N, int K, int act)
{
    __shared__ float As[BK][BM + 4];
    __shared__ float Bs[BK][BN + 4];
    const int tid = threadIdx.x;
    const int tx = tid & 15;
    const int ty = tid >> 4;
    const int row0 = blockIdx.y * BM, col0 = blockIdx.x * BN;

    const int arow = tid >> 1;
    const int ak0  = (tid & 1) * 8;
    const int gr_a = row0 + arow;

    const int bk = tid >> 4;
    const int bn = (tid & 15) * 4;

    float acc[8][4] = {};

    for (int kt = 0; kt < K; kt += BK) {
        float2 av[4];
        #pragma unroll
        for (int j = 0; j < 4; ++j) {
            int gk = kt + ak0 + 2 * j;
            float2 v = {0.f, 0.f};
            if (gr_a < M && gk < K) {
                const float* p = A + (size_t)gr_a * K + gk;
                if (gk + 1 < K) v = *(const float2*)p;
                else            v.x = *p;
            }
            av[j] = v;
        }
        float4 bv = {0.f, 0.f, 0.f, 0.f};
        {
            int gk = kt + bk;
            if (gk < K) bv = *(const float4*)(B + (size_t)gk * N + col0 + bn);
        }

        __syncthreads();
        #pragma unroll
        for (int j = 0; j < 4; ++j) {
            As[ak0 + 2*j    ][arow] = av[j].x;
            As[ak0 + 2*j + 1][arow] = av[j].y;
        }
        *(float4*)&Bs[bk][bn] = bv;
        __syncthreads();

        #pragma unroll
        for (int k = 0; k < BK; ++k) {
            float4 a0 = *(const float4*)&As[k][ty * 8];
            float4 a1 = *(const float4*)&As[k][ty * 8 + 4];
            float4 b  = *(const float4*)&Bs[k][tx * 4];
            float am[8] = {a0.x, a0.y, a0.z, a0.w, a1.x, a1.y, a1.z, a1.w};
            #pragma unroll
            for (int i = 0; i < 8; ++i) {
                acc[i][0] += am[i] * b.x;
                acc[i][1] += am[i] * b.y;
                acc[i][2] += am[i] * b.z;
                acc[i][3] += am[i] * b.w;
            }
        }
    }

    const int gc = col0 + tx * 4;
    float bb0 = bias ? bias[gc + 0] : 0.f;
    float bb1 = bias ? bias[gc + 1] : 0.f;
    float bb2 = bias ? bias[gc + 2] : 0.f;
    float bb3 = bias ? bias[gc + 3] : 0.f;
    #pragma unroll
    for (int i = 0; i < 8; ++i) {
        int gr = row0 + ty * 8 + i;
        if (gr < M) {
            float4 v;
            v.x = acc[i][0] + bb0; v.y = acc[i][1] + bb1;
            v.z = acc[i][2] + bb2; v.w = acc[i][3] + bb3;
            if (act) { v.x = fmaxf(v.x, 0.f); v.y = fmaxf(v.y, 0.f);
                       v.z = fmaxf(v.z, 0.f); v.w = fmaxf(v.w, 0.f); }
            *(float4*)(C + (size_t)gr * N + gc) = v;
        }
    }
}

// ------------- a_s[n,h], a_d[n,h]: one wave per (n,h) pair -------------
__global__ __launch_bounds__(256) void as_ad_kernel(
    const float* __restrict__ hfeat, const float* __restrict__ atts,
    const float* __restrict__ attd, float* __restrict__ a_s, float* __restrict__ a_d)
{
    const int gw = blockIdx.x * 4 + (threadIdx.x >> 6);
    const int lane = threadIdx.x & 63;
    if (gw >= N_NODES * NH) return;
    const int n = gw >> 2, h = gw & 3;
    const float* hp = hfeat + (size_t)n * (NH * DIM) + h * DIM;
    float2 hv = *(const float2*)(hp + lane * 2);
    float2 sv = *(const float2*)(atts + h * DIM + lane * 2);
    float2 dv = *(const float2*)(attd + h * DIM + lane * 2);
    float s = hv.x * sv.x + hv.y * sv.y;
    float d = hv.x * dv.x + hv.y * dv.y;
    #pragma unroll
    for (int off = 32; off > 0; off >>= 1) {
        s += __shfl_down(s, off);
        d += __shfl_down(d, off);
    }
    if (lane == 0) { a_s[n * 4 + h] = s; a_d[n * 4 + h] = d; }
}

// ------------- rel attention table[r,h] -------------
__global__ __launch_bounds__(128) void rel_table_kernel(
    const float* __restrict__ rel_emb, const float* __restrict__ line,
    const float* __restrict__ atte, float* __restrict__ table)
{
    __shared__ float we[32][NH];
    const int tid = threadIdx.x;
    const int k = tid >> 2, h = tid & 3;
    float acc = 0.f;
    for (int d = 0; d < DIM; ++d)
        acc += line[(size_t)k * (NH * DIM) + h * DIM + d] * atte[h * DIM + d];
    we[k][h] = acc;
    __syncthreads();
    if (tid < 26 * NH) {
        int r = tid >> 2, hh = tid & 3;
        float t = 0.f;
        for (int kk = 0; kk < 32; ++kk) t += rel_emb[r * 32 + kk] * we[kk][hh];
        table[r * 4 + hh] = t;
    }
}

// ================= CSR build (once per launch; topology only) =================
__global__ __launch_bounds__(256) void hist_kernel(
    const int* __restrict__ dst, int* __restrict__ cnt)
{
    const int e = blockIdx.x * blockDim.x + threadIdx.x;
    if (e >= N_EDGES) return;
    atomicAdd(&cnt[dst[e]], 1);
}

// single-block exclusive scan of cnt[20000] -> ptr[20001], ptr_copy[20000]
__global__ __launch_bounds__(1024) void scan_kernel(
    const int* __restrict__ cnt, int* __restrict__ ptr, int* __restrict__ ptr_copy)
{
    __shared__ int tsum[1024];
    const int tid = threadIdx.x;
    const int CH = 20;                       // 1024*20 >= 20000
    const int base = tid * CH;
    int s = 0;
    #pragma unroll
    for (int i = 0; i < CH; ++i) {
        int idx = base + i;
        if (idx < N_NODES) s += cnt[idx];
    }
    tsum[tid] = s;
    __syncthreads();
    for (int off = 1; off < 1024; off <<= 1) {
        int v = (tid >= off) ? tsum[tid - off] : 0;
        __syncthreads();
        tsum[tid] += v;
        __syncthreads();
    }
    int run = (tid == 0) ? 0 : tsum[tid - 1];
    #pragma unroll
    for (int i = 0; i < CH; ++i) {
        int idx = base + i;
        if (idx < N_NODES) {
            ptr[idx] = run;
            ptr_copy[idx] = run;
            run += cnt[idx];
        }
    }
    if (tid == 0) ptr[N_NODES] = N_EDGES;
}

__global__ __launch_bounds__(256) void scatter_kernel(
    const int* __restrict__ src, const int* __restrict__ dst, const int* __restrict__ etype,
    int* __restrict__ ptr_copy, int* __restrict__ src_s, int* __restrict__ etype_s)
{
    const int e = blockIdx.x * blockDim.x + threadIdx.x;
    if (e >= N_EDGES) return;
    const int d = dst[e];
    const int pos = atomicAdd(&ptr_copy[d], 1);
    src_s[pos] = src[e];
    etype_s[pos] = etype[e];
}

// ===== fused per-node GAT: softmax + self-loop + aggregate + bias + relu =====
// One wave per node. Unnormalized per-head accumulation (normalization is
// linear), single plain store. No atomics anywhere.
__global__ __launch_bounds__(256) void node_agg_kernel(
    const int* __restrict__ ptr, const int* __restrict__ src_s, const int* __restrict__ etype_s,
    const float* __restrict__ a_s, const float* __restrict__ a_d,
    const float* __restrict__ table, const float* __restrict__ hfeat,
    const float* __restrict__ bias, float* __restrict__ out)
{
    const int n = blockIdx.x * 4 + (threadIdx.x >> 6);
    const int lane = threadIdx.x & 63;
    if (n >= N_NODES) return;
    const int beg = ptr[n], end = ptr[n + 1];
    const int c = lane * 2;

    const float4 ad4 = *(const float4*)(a_d + n * 4);
    float2 acc0 = {0,0}, acc1 = {0,0}, acc2 = {0,0}, acc3 = {0,0};
    float d0 = 0, d1 = 0, d2 = 0, d3 = 0;          // denom per head
    float e0 = 0, e1 = 0, e2 = 0, e3 = 0;          // aesum per head

    for (int j = beg; j < end; ++j) {
        const int s = src_s[j];
        const int t = etype_s[j];
        const float4 as4 = *(const float4*)(a_s + s * 4);
        const float4 tv  = *(const float4*)(table + t * 4);
        const float p0 = __expf(lrelu02(as4.x + ad4.x + tv.x));
        const float p1 = __expf(lrelu02(as4.y + ad4.y + tv.y));
        const float p2 = __expf(lrelu02(as4.z + ad4.z + tv.z));
        const float p3 = __expf(lrelu02(as4.w + ad4.w + tv.w));
        e0 += tv.x; e1 += tv.y; e2 += tv.z; e3 += tv.w;
        d0 += p0; d1 += p1; d2 += p2; d3 += p3;
        const float* hp = hfeat + (size_t)s * (NH * DIM);
        const float2 v0 = *(const float2*)(hp + c);
        const float2 v1 = *(const float2*)(hp + DIM + c);
        const float2 v2 = *(const float2*)(hp + 2 * DIM + c);
        const float2 v3 = *(const float2*)(hp + 3 * DIM + c);
        acc0.x += p0 * v0.x; acc0.y += p0 * v0.y;
        acc1.x += p1 * v1.x; acc1.y += p1 * v1.y;
        acc2.x += p2 * v2.x; acc2.y += p2 * v2.y;
        acc3.x += p3 * v3.x; acc3.y += p3 * v3.y;
    }

    // self-loop: ea = aesum/deg (fill_value='mean'); logit = a_s[n]+a_d[n]+ea@we
    const float inv = 1.0f / fmaxf((float)(end - beg), 1.0f);
    const float4 asn = *(const float4*)(a_s + n * 4);
    const float p0 = __expf(lrelu02(asn.x + ad4.x + e0 * inv));
    const float p1 = __expf(lrelu02(asn.y + ad4.y + e1 * inv));
    const float p2 = __expf(lrelu02(asn.z + ad4.z + e2 * inv));
    const float p3 = __expf(lrelu02(asn.w + ad4.w + e3 * inv));
    d0 += p0; d1 += p1; d2 += p2; d3 += p3;
    {
        const float* hp = hfeat + (size_t)n * (NH * DIM);
        const float2 v0 = *(const float2*)(hp + c);
        const float2 v1 = *(const float2*)(hp + DIM + c);
        const float2 v2 = *(const float2*)(hp + 2 * DIM + c);
        const float2 v3 = *(const float2*)(hp + 3 * DIM + c);
        acc0.x += p0 * v0.x; acc0.y += p0 * v0.y;
        acc1.x += p1 * v1.x; acc1.y += p1 * v1.y;
        acc2.x += p2 * v2.x; acc2.y += p2 * v2.y;
        acc3.x += p3 * v3.x; acc3.y += p3 * v3.y;
    }

    const float i0 = 0.25f / (d0 + 1e-16f);   // 0.25 = head mean folded in
    const float i1 = 0.25f / (d1 + 1e-16f);
    const float i2 = 0.25f / (d2 + 1e-16f);
    const float i3 = 0.25f / (d3 + 1e-16f);
    const float2 b = *(const float2*)(bias + c);
    float2 o;
    o.x = fmaxf(i0 * acc0.x + i1 * acc1.x + i2 * acc2.x + i3 * acc3.x + b.x, 0.f);
    o.y = fmaxf(i0 * acc0.y + i1 * acc1.y + i2 * acc2.y + i3 * acc3.y + b.y, 0.f);
    *(float2*)(out + (size_t)n * DIM + c) = o;
}

extern "C" void kernel_launch(void* const* d_in, const int* in_sizes, int n_in,
                              void* d_out, int out_size, void* d_ws, size_t ws_size,
                              hipStream_t stream)
{
    const float* x       = (const float*)d_in[0];
    const int*   eidx    = (const int*)d_in[1];
    const int*   etype   = (const int*)d_in[2];
    const float* w1      = (const float*)d_in[3];
    const float* b1      = (const float*)d_in[4];
    const float* w2      = (const float*)d_in[5];
    const float* b2      = (const float*)d_in[6];
    const float* rel_emb = (const float*)d_in[7];
    const float* lin[2]  = {(const float*)d_in[8],  (const float*)d_in[14]};
    const float* line[2] = {(const float*)d_in[9],  (const float*)d_in[15]};
    const float* atts[2] = {(const float*)d_in[10], (const float*)d_in[16]};
    const float* attd[2] = {(const float*)d_in[11], (const float*)d_in[17]};
    const float* atte[2] = {(const float*)d_in[12], (const float*)d_in[18]};
    const float* bias[2] = {(const float*)d_in[13], (const float*)d_in[19]};
    const int* src = eidx;
    const int* dst = eidx + N_EDGES;

    float* wsf   = (float*)d_ws;
    float* hfeat = wsf;                                   // N*512 (encoder hidden aliases)
    float* xbuf  = hfeat + (size_t)N_NODES * (NH * DIM);  // N*128
    float* a_s   = xbuf + (size_t)N_NODES * DIM;          // N*4
    float* a_d   = a_s + N_NODES * 4;                     // N*4
    float* table = a_d + N_NODES * 4;                     // 128
    int*   iws   = (int*)(table + 128);
    int*   cnt_i = iws;                                   // N
    int*   ptr   = cnt_i + N_NODES;                       // N+1
    int*   ptrc  = ptr + N_NODES + 1;                     // N
    int*   src_s = ptrc + N_NODES;                        // E
    int*   ety_s = src_s + N_EDGES;                       // E

    const int mtiles = (N_NODES + BM - 1) / BM;

    // ---- CSR build (topology fixed across layers) ----
    hipMemsetAsync(cnt_i, 0, N_NODES * sizeof(int), stream);
    hist_kernel<<<(N_EDGES + 255) / 256, 256, 0, stream>>>(dst, cnt_i);
    scan_kernel<<<1, 1024, 0, stream>>>(cnt_i, ptr, ptrc);
    scatter_kernel<<<(N_EDGES + 255) / 256, 256, 0, stream>>>(src, dst, etype, ptrc, src_s, ety_s);

    // ---- node encoder ----
    gemm_bias_act<<<dim3(HIDDEN / BN, mtiles), 256, 0, stream>>>(x, w1, b1, hfeat, N_NODES, HIDDEN, F_IN, 1);
    gemm_bias_act<<<dim3(DIM / BN, mtiles), 256, 0, stream>>>(hfeat, w2, b2, xbuf, N_NODES, DIM, HIDDEN, 0);

    for (int L = 0; L < 2; ++L) {
        float* outp = (L == 0) ? xbuf : (float*)d_out;   // safe: xbuf dead after gemm

        gemm_bias_act<<<dim3((NH * DIM) / BN, mtiles), 256, 0, stream>>>(
            xbuf, lin[L], nullptr, hfeat, N_NODES, NH * DIM, DIM, 0);
        as_ad_kernel<<<N_NODES, 256, 0, stream>>>(hfeat, atts[L], attd[L], a_s, a_d);
        rel_table_kernel<<<1, 128, 0, stream>>>(rel_emb, line[L], atte[L], table);
        node_agg_kernel<<<(N_NODES + 3) / 4, 256, 0, stream>>>(
            ptr, src_s, ety_s, a_s, a_d, table, hfeat, bias[L], outp);
    }
}

// Round 4
// 607.809 us; speedup vs baseline: 2.1508x; 1.0971x over previous
//
#include <hip/hip_runtime.h>
#include <math.h>

#define N_NODES 20000
#define N_EDGES 320000
#define F_IN    518
#define HIDDEN  256
#define DIM     128
#define NH      4

typedef __attribute__((ext_vector_type(8))) short bf16x8;
typedef __attribute__((ext_vector_type(4))) float f32x4;

__device__ __forceinline__ float lrelu02(float x) { return x > 0.f ? x : 0.2f * x; }

// ========== split-bf16 MFMA GEMM: C[M,N] = act(A@B + bias) ==========
// A fp32 [M,K] converted to bf16 hi/lo during LDS staging (truncation split).
// B pre-converted to K-blocked transposed bf16: Bt[kb][n][32] (hi and lo bufs).
// C = Ah*Bh + Ah*Bl + Al*Bh  (al*bl dropped: <=2^-14 rel, ~7e-5 abs after K-sum)
// Tile: 128x128, 4 waves, each wave 64x64 = 4x4 mfma_f32_16x16x32_bf16 tiles.
__global__ __launch_bounds__(256, 2) void gemm_mfma_split(
    const float* __restrict__ A, const unsigned short* __restrict__ Bth,
    const unsigned short* __restrict__ Btl, const float* __restrict__ bias,
    float* __restrict__ C, int M, int N, int K, int act)
{
    // row stride 40 ushorts = 80 B (mult of 16 for b128; 5*16B spreads banks)
    __shared__ __align__(16) unsigned short Ash[128 * 40];
    __shared__ __align__(16) unsigned short Asl[128 * 40];
    __shared__ __align__(16) unsigned short Bsh[128 * 40];
    __shared__ __align__(16) unsigned short Bsl[128 * 40];

    const int tid = threadIdx.x;
    const int row0 = blockIdx.y * 128, col0 = blockIdx.x * 128;
    const int nkb = (K + 31) >> 5;

    // --- staging roles ---
    const int ar  = tid >> 1;          // A row 0..127
    const int ahf = tid & 1;           // k half: 0 -> k 0..15, 1 -> 16..31
    const bool avalid = (row0 + ar) < M;
    const float* aptr = A + (size_t)(row0 + ar) * K + ahf * 16;

    const int bn = tid & 127;          // B col 0..127
    const int bwhich = tid >> 7;       // 0: hi buf, 1: lo buf
    const unsigned short* bsrc = bwhich ? Btl : Bth;
    unsigned short* bdst = (bwhich ? Bsl : Bsh) + bn * 40;

    float2 astg[8];
    uint4  bstg[4];

    auto load_stage = [&](int kb) {
        const int kt = kb * 32;
        #pragma unroll
        for (int i = 0; i < 8; ++i) {
            const int col = kt + ahf * 16 + 2 * i;
            float2 v = {0.f, 0.f};
            if (avalid && col < K) v = *(const float2*)(aptr + kt + 2 * i);
            astg[i] = v;
        }
        const unsigned short* bp = bsrc + ((size_t)kb * N + col0 + bn) * 32;
        #pragma unroll
        for (int i = 0; i < 4; ++i) bstg[i] = *(const uint4*)(bp + i * 8);
    };

    auto write_stage = [&]() {
        unsigned int hp[8], lp[8];
        #pragma unroll
        for (int i = 0; i < 8; ++i) {
            unsigned int bx = __float_as_uint(astg[i].x);
            unsigned int by = __float_as_uint(astg[i].y);
            unsigned int hx = bx & 0xFFFF0000u, hy = by & 0xFFFF0000u;
            hp[i] = hy | (hx >> 16);
            float lx = astg[i].x - __uint_as_float(hx);
            float ly = astg[i].y - __uint_as_float(hy);
            lp[i] = (__float_as_uint(ly) & 0xFFFF0000u) | (__float_as_uint(lx) >> 16);
        }
        unsigned short* pa = &Ash[ar * 40 + ahf * 16];
        ((uint4*)pa)[0] = make_uint4(hp[0], hp[1], hp[2], hp[3]);
        ((uint4*)pa)[1] = make_uint4(hp[4], hp[5], hp[6], hp[7]);
        unsigned short* pl = &Asl[ar * 40 + ahf * 16];
        ((uint4*)pl)[0] = make_uint4(lp[0], lp[1], lp[2], lp[3]);
        ((uint4*)pl)[1] = make_uint4(lp[4], lp[5], lp[6], lp[7]);
        #pragma unroll
        for (int i = 0; i < 4; ++i) ((uint4*)bdst)[i] = bstg[i];
    };

    // --- compute roles ---
    const int w = tid >> 6, lane = tid & 63;
    const int wm = w & 1, wn = w >> 1;        // wave tile at (wm*64, wn*64)
    const int m16 = lane & 15, q = lane >> 4;

    f32x4 acc[4][4] = {};

    load_stage(0);
    for (int kb = 0; kb < nkb; ++kb) {
        __syncthreads();
        write_stage();
        __syncthreads();
        if (kb + 1 < nkb) load_stage(kb + 1);

        bf16x8 ah[4], al[4], bh[4], bl[4];
        #pragma unroll
        for (int mi = 0; mi < 4; ++mi) {
            const int off = (wm * 64 + mi * 16 + m16) * 40 + q * 8;
            ah[mi] = *(const bf16x8*)&Ash[off];
            al[mi] = *(const bf16x8*)&Asl[off];
        }
        #pragma unroll
        for (int ni = 0; ni < 4; ++ni) {
            const int off = (wn * 64 + ni * 16 + m16) * 40 + q * 8;
            bh[ni] = *(const bf16x8*)&Bsh[off];
            bl[ni] = *(const bf16x8*)&Bsl[off];
        }
        #pragma unroll
        for (int mi = 0; mi < 4; ++mi)
            #pragma unroll
            for (int ni = 0; ni < 4; ++ni)
                acc[mi][ni] = __builtin_amdgcn_mfma_f32_16x16x32_bf16(ah[mi], bh[ni], acc[mi][ni], 0, 0, 0);
        #pragma unroll
        for (int mi = 0; mi < 4; ++mi)
            #pragma unroll
            for (int ni = 0; ni < 4; ++ni)
                acc[mi][ni] = __builtin_amdgcn_mfma_f32_16x16x32_bf16(ah[mi], bl[ni], acc[mi][ni], 0, 0, 0);
        #pragma unroll
        for (int mi = 0; mi < 4; ++mi)
            #pragma unroll
            for (int ni = 0; ni < 4; ++ni)
                acc[mi][ni] = __builtin_amdgcn_mfma_f32_16x16x32_bf16(al[mi], bh[ni], acc[mi][ni], 0, 0, 0);
    }

    // epilogue: C/D layout row=(lane>>4)*4+reg, col=lane&15 (verified m89/m91)
    #pragma unroll
    for (int ni = 0; ni < 4; ++ni) {
        const int col = col0 + wn * 64 + ni * 16 + m16;
        const float bb = bias ? bias[col] : 0.f;
        #pragma unroll
        for (int mi = 0; mi < 4; ++mi) {
            const int rbase = row0 + wm * 64 + mi * 16 + q * 4;
            #pragma unroll
            for (int r = 0; r < 4; ++r) {
                const int row = rbase + r;
                if (row < M) {
                    float v = acc[mi][ni][r] + bb;
                    if (act) v = fmaxf(v, 0.f);
                    C[(size_t)row * N + col] = v;
                }
            }
        }
    }
}

// ---- weight conversion: w[K,N] fp32 -> Bt hi/lo bf16, layout [kb][n][32] ----
__global__ __launch_bounds__(256) void conv_b_kernel(
    const float* __restrict__ w, unsigned short* __restrict__ bh,
    unsigned short* __restrict__ bl, int K, int N, int total)
{
    const int idx = blockIdx.x * 256 + threadIdx.x;
    if (idx >= total) return;
    const int ki = idx & 31;
    const int rem = idx >> 5;        // kb*N + n
    const int n = rem % N;
    const int kb = rem / N;
    const int k = kb * 32 + ki;
    const float v = (k < K) ? w[(size_t)k * N + n] : 0.f;
    const unsigned int b = __float_as_uint(v);
    const unsigned int h = b & 0xFFFF0000u;
    bh[idx] = (unsigned short)(h >> 16);
    const float lo = v - __uint_as_float(h);
    bl[idx] = (unsigned short)(__float_as_uint(lo) >> 16);
}

// ------------- a_s[n,h], a_d[n,h]: one wave per (n,h) pair -------------
__global__ __launch_bounds__(256) void as_ad_kernel(
    const float* __restrict__ hfeat, const float* __restrict__ atts,
    const float* __restrict__ attd, float* __restrict__ a_s, float* __restrict__ a_d)
{
    const int gw = blockIdx.x * 4 + (threadIdx.x >> 6);
    const int lane = threadIdx.x & 63;
    if (gw >= N_NODES * NH) return;
    const int n = gw >> 2, h = gw & 3;
    const float* hp = hfeat + (size_t)n * (NH * DIM) + h * DIM;
    float2 hv = *(const float2*)(hp + lane * 2);
    float2 sv = *(const float2*)(atts + h * DIM + lane * 2);
    float2 dv = *(const float2*)(attd + h * DIM + lane * 2);
    float s = hv.x * sv.x + hv.y * sv.y;
    float d = hv.x * dv.x + hv.y * dv.y;
    #pragma unroll
    for (int off = 32; off > 0; off >>= 1) {
        s += __shfl_down(s, off);
        d += __shfl_down(d, off);
    }
    if (lane == 0) { a_s[n * 4 + h] = s; a_d[n * 4 + h] = d; }
}

// ------------- rel attention table[r,h] -------------
__global__ __launch_bounds__(128) void rel_table_kernel(
    const float* __restrict__ rel_emb, const float* __restrict__ line,
    const float* __restrict__ atte, float* __restrict__ table)
{
    __shared__ float we[32][NH];
    const int tid = threadIdx.x;
    const int k = tid >> 2, h = tid & 3;
    float acc = 0.f;
    for (int d = 0; d < DIM; ++d)
        acc += line[(size_t)k * (NH * DIM) + h * DIM + d] * atte[h * DIM + d];
    we[k][h] = acc;
    __syncthreads();
    if (tid < 26 * NH) {
        int r = tid >> 2, hh = tid & 3;
        float t = 0.f;
        for (int kk = 0; kk < 32; ++kk) t += rel_emb[r * 32 + kk] * we[kk][hh];
        table[r * 4 + hh] = t;
    }
}

// ================= CSR build (once per launch; topology only) =================
__global__ __launch_bounds__(256) void hist_kernel(
    const int* __restrict__ dst, int* __restrict__ cnt)
{
    const int e = blockIdx.x * blockDim.x + threadIdx.x;
    if (e >= N_EDGES) return;
    atomicAdd(&cnt[dst[e]], 1);
}

__global__ __launch_bounds__(1024) void scan_kernel(
    const int* __restrict__ cnt, int* __restrict__ ptr, int* __restrict__ ptr_copy)
{
    __shared__ int tsum[1024];
    const int tid = threadIdx.x;
    const int CH = 20;
    const int base = tid * CH;
    int s = 0;
    #pragma unroll
    for (int i = 0; i < CH; ++i) {
        int idx = base + i;
        if (idx < N_NODES) s += cnt[idx];
    }
    tsum[tid] = s;
    __syncthreads();
    for (int off = 1; off < 1024; off <<= 1) {
        int v = (tid >= off) ? tsum[tid - off] : 0;
        __syncthreads();
        tsum[tid] += v;
        __syncthreads();
    }
    int run = (tid == 0) ? 0 : tsum[tid - 1];
    #pragma unroll
    for (int i = 0; i < CH; ++i) {
        int idx = base + i;
        if (idx < N_NODES) {
            ptr[idx] = run;
            ptr_copy[idx] = run;
            run += cnt[idx];
        }
    }
    if (tid == 0) ptr[N_NODES] = N_EDGES;
}

__global__ __launch_bounds__(256) void scatter_kernel(
    const int* __restrict__ src, const int* __restrict__ dst, const int* __restrict__ etype,
    int* __restrict__ ptr_copy, int* __restrict__ src_s, int* __restrict__ etype_s)
{
    const int e = blockIdx.x * blockDim.x + threadIdx.x;
    if (e >= N_EDGES) return;
    const int d = dst[e];
    const int pos = atomicAdd(&ptr_copy[d], 1);
    src_s[pos] = src[e];
    etype_s[pos] = etype[e];
}

// ===== fused per-node GAT: softmax + self-loop + aggregate + bias + relu =====
__global__ __launch_bounds__(256) void node_agg_kernel(
    const int* __restrict__ ptr, const int* __restrict__ src_s, const int* __restrict__ etype_s,
    const float* __restrict__ a_s, const float* __restrict__ a_d,
    const float* __restrict__ table, const float* __restrict__ hfeat,
    const float* __restrict__ bias, float* __restrict__ out)
{
    const int n = blockIdx.x * 4 + (threadIdx.x >> 6);
    const int lane = threadIdx.x & 63;
    if (n >= N_NODES) return;
    const int beg = ptr[n], end = ptr[n + 1];
    const int c = lane * 2;

    const float4 ad4 = *(const float4*)(a_d + n * 4);
    float2 acc0 = {0,0}, acc1 = {0,0}, acc2 = {0,0}, acc3 = {0,0};
    float d0 = 0, d1 = 0, d2 = 0, d3 = 0;
    float e0 = 0, e1 = 0, e2 = 0, e3 = 0;

    for (int j = beg; j < end; ++j) {
        const int s = src_s[j];
        const int t = etype_s[j];
        const float4 as4 = *(const float4*)(a_s + s * 4);
        const float4 tv  = *(const float4*)(table + t * 4);
        const float p0 = __expf(lrelu02(as4.x + ad4.x + tv.x));
        const float p1 = __expf(lrelu02(as4.y + ad4.y + tv.y));
        const float p2 = __expf(lrelu02(as4.z + ad4.z + tv.z));
        const float p3 = __expf(lrelu02(as4.w + ad4.w + tv.w));
        e0 += tv.x; e1 += tv.y; e2 += tv.z; e3 += tv.w;
        d0 += p0; d1 += p1; d2 += p2; d3 += p3;
        const float* hp = hfeat + (size_t)s * (NH * DIM);
        const float2 v0 = *(const float2*)(hp + c);
        const float2 v1 = *(const float2*)(hp + DIM + c);
        const float2 v2 = *(const float2*)(hp + 2 * DIM + c);
        const float2 v3 = *(const float2*)(hp + 3 * DIM + c);
        acc0.x += p0 * v0.x; acc0.y += p0 * v0.y;
        acc1.x += p1 * v1.x; acc1.y += p1 * v1.y;
        acc2.x += p2 * v2.x; acc2.y += p2 * v2.y;
        acc3.x += p3 * v3.x; acc3.y += p3 * v3.y;
    }

    const float inv = 1.0f / fmaxf((float)(end - beg), 1.0f);
    const float4 asn = *(const float4*)(a_s + n * 4);
    const float p0 = __expf(lrelu02(asn.x + ad4.x + e0 * inv));
    const float p1 = __expf(lrelu02(asn.y + ad4.y + e1 * inv));
    const float p2 = __expf(lrelu02(asn.z + ad4.z + e2 * inv));
    const float p3 = __expf(lrelu02(asn.w + ad4.w + e3 * inv));
    d0 += p0; d1 += p1; d2 += p2; d3 += p3;
    {
        const float* hp = hfeat + (size_t)n * (NH * DIM);
        const float2 v0 = *(const float2*)(hp + c);
        const float2 v1 = *(const float2*)(hp + DIM + c);
        const float2 v2 = *(const float2*)(hp + 2 * DIM + c);
        const float2 v3 = *(const float2*)(hp + 3 * DIM + c);
        acc0.x += p0 * v0.x; acc0.y += p0 * v0.y;
        acc1.x += p1 * v1.x; acc1.y += p1 * v1.y;
        acc2.x += p2 * v2.x; acc2.y += p2 * v2.y;
        acc3.x += p3 * v3.x; acc3.y += p3 * v3.y;
    }

    const float i0 = 0.25f / (d0 + 1e-16f);
    const float i1 = 0.25f / (d1 + 1e-16f);
    const float i2 = 0.25f / (d2 + 1e-16f);
    const float i3 = 0.25f / (d3 + 1e-16f);
    const float2 b = *(const float2*)(bias + c);
    float2 o;
    o.x = fmaxf(i0 * acc0.x + i1 * acc1.x + i2 * acc2.x + i3 * acc3.x + b.x, 0.f);
    o.y = fmaxf(i0 * acc0.y + i1 * acc1.y + i2 * acc2.y + i3 * acc3.y + b.y, 0.f);
    *(float2*)(out + (size_t)n * DIM + c) = o;
}

extern "C" void kernel_launch(void* const* d_in, const int* in_sizes, int n_in,
                              void* d_out, int out_size, void* d_ws, size_t ws_size,
                              hipStream_t stream)
{
    const float* x       = (const float*)d_in[0];
    const int*   eidx    = (const int*)d_in[1];
    const int*   etype   = (const int*)d_in[2];
    const float* w1      = (const float*)d_in[3];
    const float* b1      = (const float*)d_in[4];
    const float* w2      = (const float*)d_in[5];
    const float* b2      = (const float*)d_in[6];
    const float* rel_emb = (const float*)d_in[7];
    const float* lin[2]  = {(const float*)d_in[8],  (const float*)d_in[14]};
    const float* line[2] = {(const float*)d_in[9],  (const float*)d_in[15]};
    const float* atts[2] = {(const float*)d_in[10], (const float*)d_in[16]};
    const float* attd[2] = {(const float*)d_in[11], (const float*)d_in[17]};
    const float* atte[2] = {(const float*)d_in[12], (const float*)d_in[18]};
    const float* bias[2] = {(const float*)d_in[13], (const float*)d_in[19]};
    const int* src = eidx;
    const int* dst = eidx + N_EDGES;

    float* wsf   = (float*)d_ws;
    float* hfeat = wsf;                                   // N*512
    float* xbuf  = hfeat + (size_t)N_NODES * (NH * DIM);  // N*128
    float* a_s   = xbuf + (size_t)N_NODES * DIM;          // N*4
    float* a_d   = a_s + N_NODES * 4;                     // N*4
    float* table = a_d + N_NODES * 4;                     // 128
    unsigned short* b1h = (unsigned short*)(table + 128); // 17*256*32
    unsigned short* b1l = b1h + 17 * 256 * 32;
    unsigned short* b2h = b1l + 17 * 256 * 32;            // 8*128*32
    unsigned short* b2l = b2h + 8 * 128 * 32;
    unsigned short* b3h = b2l + 8 * 128 * 32;             // 4*512*32
    unsigned short* b3l = b3h + 4 * 512 * 32;
    unsigned short* b4h = b3l + 4 * 512 * 32;
    unsigned short* b4l = b4h + 4 * 512 * 32;
    int*   iws   = (int*)(b4l + 4 * 512 * 32);
    int*   cnt_i = iws;                                   // N
    int*   ptr   = cnt_i + N_NODES;                       // N+1
    int*   ptrc  = ptr + N_NODES + 1;                     // N
    int*   src_s = ptrc + N_NODES;                        // E
    int*   ety_s = src_s + N_EDGES;                       // E

    const int mtiles = (N_NODES + 127) / 128;             // 157

    // ---- weight conversions (const inputs -> same work every call) ----
    conv_b_kernel<<<(17*256*32 + 255)/256, 256, 0, stream>>>(w1, b1h, b1l, F_IN, HIDDEN, 17*256*32);
    conv_b_kernel<<<(8*128*32 + 255)/256, 256, 0, stream>>>(w2, b2h, b2l, HIDDEN, DIM, 8*128*32);
    conv_b_kernel<<<(4*512*32 + 255)/256, 256, 0, stream>>>(lin[0], b3h, b3l, DIM, NH*DIM, 4*512*32);
    conv_b_kernel<<<(4*512*32 + 255)/256, 256, 0, stream>>>(lin[1], b4h, b4l, DIM, NH*DIM, 4*512*32);

    // ---- CSR build ----
    hipMemsetAsync(cnt_i, 0, N_NODES * sizeof(int), stream);
    hist_kernel<<<(N_EDGES + 255) / 256, 256, 0, stream>>>(dst, cnt_i);
    scan_kernel<<<1, 1024, 0, stream>>>(cnt_i, ptr, ptrc);
    scatter_kernel<<<(N_EDGES + 255) / 256, 256, 0, stream>>>(src, dst, etype, ptrc, src_s, ety_s);

    // ---- node encoder ----
    gemm_mfma_split<<<dim3(HIDDEN / 128, mtiles), 256, 0, stream>>>(
        x, b1h, b1l, b1, hfeat, N_NODES, HIDDEN, F_IN, 1);
    gemm_mfma_split<<<dim3(DIM / 128, mtiles), 256, 0, stream>>>(
        hfeat, b2h, b2l, b2, xbuf, N_NODES, DIM, HIDDEN, 0);

    for (int L = 0; L < 2; ++L) {
        float* outp = (L == 0) ? xbuf : (float*)d_out;
        const unsigned short* bh = (L == 0) ? b3h : b4h;
        const unsigned short* bl = (L == 0) ? b3l : b4l;

        gemm_mfma_split<<<dim3((NH * DIM) / 128, mtiles), 256, 0, stream>>>(
            xbuf, bh, bl, nullptr, hfeat, N_NODES, NH * DIM, DIM, 0);
        as_ad_kernel<<<N_NODES, 256, 0, stream>>>(hfeat, atts[L], attd[L], a_s, a_d);
        rel_table_kernel<<<1, 128, 0, stream>>>(rel_emb, line[L], atte[L], table);
        node_agg_kernel<<<(N_NODES + 3) / 4, 256, 0, stream>>>(
            ptr, src_s, ety_s, a_s, a_d, table, hfeat, bias[L], outp);
    }
}